// Round 11
// baseline (200.979 us; speedup 1.0000x reference)
//
#include <hip/hip_runtime.h>

// N=4096, D=1024 self-attention, all GEMMs NT-form bf16 MFMA (16x16x32), fp32 acc.
// R4: BK=64 + XOR swizzle. R5: XCD swizzle. R7: softmax fused into epilogues.
// R12: V-transpose fused into k_qkv (MODE 3).
// R14 (REVERTED): BK=32 ring. R15 (REVERTED): split-K atomics.
// R16 (WIN, 213->207): k_score counted-vmcnt double-buffer (T3+T4+T5).
// R17 (WIN, 207->200): same on k_pv. R18 (WIN, 200->197.7): on k_qkv.
// R19/R20 (NEUTRAL, ->196.8): k_score 8-phase 256x256. Kept.
// R21 (REVERTED, 272): fused-QKV blew registers + BK=32 bank conflicts.
//   RULE: the chunk-XOR swizzle needs BK=64 row stride.
// R22 (WIN, ->194.5): rowsum atomics -> per-bx partials (LDS reduce).
// R23 (NEUTRAL, ->195.3): k_score operand swap (s16x4 SP stores, 2-shfl
//   rowsum). Kept: per-dispatch k_score 67->44.6; GEMMs now balanced ~44.5.
// R24: k_pv 128x64/256thr -> 128x128/512thr (same 2-phase counted template,
//   R15's tile minus the atomics that killed it): SP staged 8x not 16x
//   (805->512MB total staging), MFMA/staged-row 0.33->0.5, vmcnt(4),
//   LDS 2x32KB, grid (8,32)=256 blocks -- k_score's proven config class.
//
// ws layout:
//   Qb bf16[4096,1024] @ 0      Kb @ 8MB     Vt bf16[1024,4096] @ 24MB
//   SP bf16[4096,4096] @ 32MB   (exp'd scores; spans 32..64MB)
//   xb @ 32MB (overlaps SP; dead before k_score), Wqb @ 40MB, Wkb @ 42MB, Wvb @ 44MB
//   rowsum_p fp32[16][4096] @ 64MB (past SP; ws >= 112MB proven in R3)

#define N_TOK 4096
#define DDIM  1024

typedef short s16x4 __attribute__((ext_vector_type(4)));
typedef short s16x8 __attribute__((ext_vector_type(8)));
typedef float f32x4 __attribute__((ext_vector_type(4)));

#define VMCNT0() asm volatile("s_waitcnt vmcnt(0)" ::: "memory")
#define VMCNT4() asm volatile("s_waitcnt vmcnt(4)" ::: "memory")
#define VMCNT8() asm volatile("s_waitcnt vmcnt(8)" ::: "memory")
#define LGKMCNT0() asm volatile("s_waitcnt lgkmcnt(0)" ::: "memory")
#define SCHEDB() __builtin_amdgcn_sched_barrier(0)
#define BARRIER() do { asm volatile("" ::: "memory"); \
                       __builtin_amdgcn_s_barrier();  \
                       asm volatile("" ::: "memory"); } while (0)

__device__ inline short f2b(float f) {
  unsigned int u = __float_as_uint(f);
  unsigned int r = (u + 0x7FFFu + ((u >> 16) & 1u)) >> 16;
  return (short)(unsigned short)r;
}

__device__ __forceinline__ void gld_lds16(const short* g, short* l) {
  __builtin_amdgcn_global_load_lds(
      (const __attribute__((address_space(1))) unsigned int*)g,
      (__attribute__((address_space(3))) unsigned int*)l, 16, 0, 0);
}

// XCD-locality remap, GY=32 grids: XCD (L%8) owns a 4-row-tile band.
__device__ __forceinline__ void xcd_remap(int gx, int& bx, int& by) {
  const int L = by * gx + bx;
  const int g = L & 7, h = L >> 3;
  by = g * 4 + (h & 3);
  bx = h >> 2;
}
// 256-tile variant: XCD owns a 2-row-tile band.
__device__ __forceinline__ void xcd_remap16(int gx, int& bx, int& by) {
  const int L = by * gx + bx;
  const int g = L & 7, h = L >> 3;
  by = g * 2 + (h & 1);
  bx = h >> 1;
}

// ---------------------------------------------------------------------------
// R18 pipelined 128x128 BK=64 NT GEMM (R16 schedule). MODE epilogues:
//   0: bf16 store of scale*acc + bias                  (aux = bias)
//   3: bf16 TRANSPOSED store of acc + bias             (aux = bias)
// smem: 2 slots x 16384 shorts (64 KiB). ldA == ldB == ld.
// ---------------------------------------------------------------------------
template<int MODE>
__device__ __forceinline__ void gemm_pipe128(
    const short* __restrict__ A, const short* __restrict__ B,
    void* __restrict__ C, const float* __restrict__ aux,
    short (*smem)[(128 + 128) * 64],
    int K, int ld, int ldc, float scale, int row0, int col0)
{
  constexpr int BM = 128, BN = 128, BK = 64;
  const int NT = K / BK;

  const int tid  = threadIdx.x;
  const int wave = tid >> 6, lane = tid & 63;
  const int wm = wave >> 1, wn = wave & 1;      // 2x2 waves, 64x64 out each
  const int quad = lane >> 4, lr = lane & 15;

  auto stage = [&](int t, int sl) {
    #pragma unroll
    for (int c = 0; c < 8; c++) {
      const int id = c * 256 + tid;             // 0..2047
      const int r  = id >> 3;                   // rows 0..255 (A:0-127, B:128-255)
      const int q  = (id & 7) ^ (r & 7);
      const short* src = (r < BM)
          ? A + (size_t)(row0 + r) * ld + t * BK + q * 8
          : B + (size_t)(col0 + r - BM) * ld + t * BK + q * 8;
      gld_lds16(src, &smem[sl][(c * 256 + wave * 64) * 8]);
    }
  };

  f32x4 acc[4][4];
  #pragma unroll
  for (int i = 0; i < 4; i++)
    #pragma unroll
    for (int j = 0; j < 4; j++) acc[i][j] = {0.f, 0.f, 0.f, 0.f};

  stage(0, 0);
  stage(1, 1);
  VMCNT8();
  BARRIER();

  for (int t = 0; t < NT; t++) {
    const int sl = t & 1;
    const short* As = smem[sl];
    const short* Bs = smem[sl] + BM * BK;

    s16x8 af[2][4], bf[2][4];
    #pragma unroll
    for (int h = 0; h < 2; h++) {
      #pragma unroll
      for (int i = 0; i < 4; i++) {
        const int row = wm * 64 + i * 16 + lr;
        const int ch = (h * 4 + quad) ^ (row & 7);
        af[h][i] = *reinterpret_cast<const s16x8*>(&As[(row * 8 + ch) * 8]);
      }
      #pragma unroll
      for (int j = 0; j < 4; j++) {
        const int row = wn * 64 + j * 16 + lr;
        const int ch = (h * 4 + quad) ^ (row & 7);
        bf[h][j] = *reinterpret_cast<const s16x8*>(&Bs[(row * 8 + ch) * 8]);
      }
    }
    LGKMCNT0();
    SCHEDB();
    BARRIER();                                   // slot sl reusable block-wide

    const bool pf = (t + 2) < NT;
    if (pf) stage(t + 2, sl);

    __builtin_amdgcn_s_setprio(1);
    #pragma unroll
    for (int h = 0; h < 2; h++)
      #pragma unroll
      for (int i = 0; i < 4; i++)
        #pragma unroll
        for (int j = 0; j < 4; j++)
          acc[i][j] = __builtin_amdgcn_mfma_f32_16x16x32_bf16(
              af[h][i], bf[h][j], acc[i][j], 0, 0, 0);
    __builtin_amdgcn_s_setprio(0);

    if (pf) { VMCNT8(); } else { VMCNT0(); }
    BARRIER();
  }
  // loop exit: all LDS reads drained (tail vmcnt(0)+barrier) -> smem reusable.

  if constexpr (MODE == 0) {
    float bb[4];
    #pragma unroll
    for (int j = 0; j < 4; j++) bb[j] = aux[col0 + wn * 64 + j * 16 + lr];
    #pragma unroll
    for (int i = 0; i < 4; i++) {
      const int r0 = row0 + wm * 64 + i * 16 + quad * 4;
      #pragma unroll
      for (int j = 0; j < 4; j++) {
        const int c = col0 + wn * 64 + j * 16 + lr;
        #pragma unroll
        for (int r = 0; r < 4; r++)
          ((short*)C)[(size_t)(r0 + r) * ldc + c] = f2b(acc[i][j][r] * scale + bb[j]);
      }
    }
  } else {
    // MODE 3: transposed bf16 store with bias. trans[col][row], stride 136.
    float bb[4];
    #pragma unroll
    for (int j = 0; j < 4; j++) bb[j] = aux[col0 + wn * 64 + j * 16 + lr];
    short* trans = &smem[0][0];                  // 128 x 136 shorts = 34816 B
    #pragma unroll
    for (int i = 0; i < 4; i++) {
      const int rl = wm * 64 + i * 16 + quad * 4;
      #pragma unroll
      for (int j = 0; j < 4; j++) {
        const int cl = wn * 64 + j * 16 + lr;
        s16x4 v;
        #pragma unroll
        for (int r = 0; r < 4; r++) v[r] = f2b(acc[i][j][r] * scale + bb[j]);
        *reinterpret_cast<s16x4*>(&trans[cl * 136 + rl]) = v;
      }
    }
    BARRIER();
    #pragma unroll
    for (int s = 0; s < 8; s++) {
      const int u = s * 256 + tid;
      const int cc = u >> 4;                     // column 0..127
      const int seg = u & 15;                    // 16 segs x 8 shorts = 128 rows
      s16x8 v = *reinterpret_cast<const s16x8*>(&trans[cc * 136 + seg * 8]);
      *reinterpret_cast<s16x8*>(
          &((short*)C)[(size_t)(col0 + cc) * ldc + row0 + seg * 8]) = v;
    }
  }
}

// ---------------------------------------------------------------------------
// fp32 -> bf16 conversion for x, Wq, Wk, Wv (one launch).
// ---------------------------------------------------------------------------
#define XU  (N_TOK * DDIM / 8)      // 524288
#define WU  (DDIM * DDIM / 8)       // 131072
#define NCVT ((XU + 3 * WU) / 256)  // 3584 convert blocks
__global__ __launch_bounds__(256)
void cvt_all(const float* __restrict__ x,  const float* __restrict__ wq,
             const float* __restrict__ wk, const float* __restrict__ wv,
             short* __restrict__ xb, short* __restrict__ wqb,
             short* __restrict__ wkb, short* __restrict__ wvb)
{
  int gid = blockIdx.x * 256 + threadIdx.x;
  const float* src; short* dst; int off;
  if (gid < XU)               { src = x;  dst = xb;  off = gid; }
  else if (gid < XU + WU)     { src = wq; dst = wqb; off = gid - XU; }
  else if (gid < XU + 2 * WU) { src = wk; dst = wkb; off = gid - XU - WU; }
  else                        { src = wv; dst = wvb; off = gid - XU - 2 * WU; }
  const float4* g = reinterpret_cast<const float4*>(src) + (size_t)off * 2;
  float4 a = g[0], b = g[1];
  s16x8 o;
  o[0] = f2b(a.x); o[1] = f2b(a.y); o[2] = f2b(a.z); o[3] = f2b(a.w);
  o[4] = f2b(b.x); o[5] = f2b(b.y); o[6] = f2b(b.z); o[7] = f2b(b.w);
  reinterpret_cast<s16x8*>(dst)[off] = o;
}

// ---------------------------------------------------------------------------
// R18 k_qkv: pipelined 128x128 BK=64; grid (8,32,3); LDS 64KB -> 2 blk/CU.
// ---------------------------------------------------------------------------
__global__ __launch_bounds__(256, 2)
void k_qkv(const short* __restrict__ xb,
           const short* __restrict__ Wqb, const short* __restrict__ Wkb,
           const short* __restrict__ Wvb,
           const float* __restrict__ bq, const float* __restrict__ bk,
           const float* __restrict__ bv,
           short* __restrict__ Qb, short* __restrict__ Kb, short* __restrict__ Vt)
{
  __shared__ short smem[2][(128 + 128) * 64];   // 64 KiB
  int bx = blockIdx.x, by = blockIdx.y;
  xcd_remap(DDIM / 128, bx, by);
  if (blockIdx.z == 0) {
    gemm_pipe128<0>(xb, Wqb, Qb, bq, smem, DDIM, DDIM, DDIM,
                    1.0f, by * 128, bx * 128);
  } else if (blockIdx.z == 1) {
    gemm_pipe128<0>(xb, Wkb, Kb, bk, smem, DDIM, DDIM, DDIM,
                    1.0f, by * 128, bx * 128);
  } else {
    gemm_pipe128<3>(xb, Wvb, Vt, bv, smem, DDIM, DDIM, N_TOK,
                    1.0f, by * 128, bx * 128);
  }
}

// ---------------------------------------------------------------------------
// R23 k_score: 8-phase 256x256 BK=64, 512 threads, 128KB LDS, OPERAND SWAP:
// mfma(A=K_frag, B=Q_frag) -> D[m=S-col][n=S-row]. Lane holds 4 consecutive
// S-cols (quad*4+r) of one S-row (lr). Epilogue: s16x4 SP stores, 2-shfl
// cross-quad rowsum, 2-partial LDS reduce, non-atomic rowsum_p[bx] store.
// ---------------------------------------------------------------------------
#define READ_MF(Bs, MH) do {                                                  \
    _Pragma("unroll")                                                         \
    for (int kh = 0; kh < 2; kh++)                                            \
      _Pragma("unroll")                                                       \
      for (int f = 0; f < 4; f++) {                                           \
        const int row_ = wm * 128 + (MH) * 64 + f * 16 + lr;                  \
        const int ch_ = (kh * 4 + quad) ^ (row_ & 7);                         \
        mf[kh][f] = *reinterpret_cast<const s16x8*>(&(Bs)[(row_ * 8 + ch_) * 8]); \
      }                                                                       \
  } while (0)

#define READ_NF(As, NH, NF) do {                                              \
    _Pragma("unroll")                                                         \
    for (int kh = 0; kh < 2; kh++)                                            \
      _Pragma("unroll")                                                       \
      for (int g = 0; g < 2; g++) {                                           \
        const int row_ = wn * 64 + (NH) * 32 + g * 16 + lr;                   \
        const int ch_ = (kh * 4 + quad) ^ (row_ & 7);                         \
        NF[kh][g] = *reinterpret_cast<const s16x8*>(&(As)[(row_ * 8 + ch_) * 8]); \
      }                                                                       \
  } while (0)

#define MFMA_Q(MH, NH, NF) do {                                               \
    __builtin_amdgcn_s_setprio(1);                                            \
    _Pragma("unroll")                                                         \
    for (int kh = 0; kh < 2; kh++)                                            \
      _Pragma("unroll")                                                       \
      for (int f = 0; f < 4; f++)                                             \
        _Pragma("unroll")                                                     \
        for (int g = 0; g < 2; g++)                                           \
          acc[(MH) * 4 + f][(NH) * 2 + g] =                                   \
              __builtin_amdgcn_mfma_f32_16x16x32_bf16(                        \
                  mf[kh][f], NF[kh][g], acc[(MH) * 4 + f][(NH) * 2 + g],      \
                  0, 0, 0);                                                   \
    __builtin_amdgcn_s_setprio(0);                                            \
  } while (0)

__global__ __launch_bounds__(512, 2)
void k_score(const short* __restrict__ Qb, const short* __restrict__ Kb,
             short* __restrict__ SP, float* __restrict__ rowsum_p)
{
  constexpr int NITER = 8;                      // 16 K-tiles, 2 per iter
  __shared__ short smem[2][32768];              // [buf][Q 256x64 | K 256x64] 128KB

  int bx = blockIdx.x, by = blockIdx.y;
  xcd_remap16(16, bx, by);
  const int row0 = by * 256, col0 = bx * 256;   // row0: Q rows, col0: K rows

  const int tid  = threadIdx.x;
  const int wave = tid >> 6, lane = tid & 63;
  const int wm = wave >> 2, wn = wave & 3;      // wm: 128 S-cols, wn: 64 S-rows
  const int quad = lane >> 4, lr = lane & 15;

  auto stage_h = [&](int t, int b, int h) {
    const short* gbase = (h < 2)
        ? Qb + (size_t)(row0 + (h & 1) * 128) * DDIM
        : Kb + (size_t)(col0 + (h & 1) * 128) * DDIM;
    short* dst = &smem[b][(h >> 1) * 16384 + (h & 1) * 8192];
    #pragma unroll
    for (int c = 0; c < 2; c++) {
      const int id = c * 512 + tid;             // 0..1023
      const int r  = id >> 3;                   // 0..127
      const int q  = (id & 7) ^ (r & 7);
      gld_lds16(gbase + (size_t)r * DDIM + t * 64 + q * 8,
                dst + (c * 512 + wave * 64) * 8);
    }
  };

  s16x8 mf[2][4], nf0[2][2], nf1[2][2];
  f32x4 acc[8][4];
  #pragma unroll
  for (int i = 0; i < 8; i++)
    #pragma unroll
    for (int j = 0; j < 4; j++) acc[i][j] = {0.f, 0.f, 0.f, 0.f};

  const short* As0 = smem[0];                   // Q half
  const short* Bs0 = smem[0] + 16384;           // K half
  const short* As1 = smem[1];
  const short* Bs1 = smem[1] + 16384;

  stage_h(0, 0, 2); stage_h(0, 0, 3); stage_h(0, 0, 0); stage_h(0, 0, 1);
  stage_h(1, 1, 2); stage_h(1, 1, 0);
  VMCNT4();
  BARRIER();

  for (int i = 0; i < NITER; i++) {
    const int t1 = 2 * i + 1;
    const bool more = (i + 1) < NITER;

    READ_MF(Bs0, 0); READ_NF(As0, 0, nf0);
    stage_h(t1, 1, 3);
    BARRIER(); LGKMCNT0(); SCHEDB();
    MFMA_Q(0, 0, nf0);
    BARRIER();
    READ_NF(As0, 1, nf1);
    stage_h(t1, 1, 1);
    BARRIER(); LGKMCNT0(); SCHEDB();
    MFMA_Q(0, 1, nf1);
    BARRIER();
    READ_MF(Bs0, 1);
    if (more) stage_h(t1 + 1, 0, 2);
    BARRIER(); LGKMCNT0(); SCHEDB();
    MFMA_Q(1, 1, nf1);
    BARRIER();
    if (more) { stage_h(t1 + 1, 0, 0); VMCNT4(); } else { VMCNT0(); }
    BARRIER();
    MFMA_Q(1, 0, nf0);
    BARRIER();
    READ_MF(Bs1, 0); READ_NF(As1, 0, nf0);
    if (more) stage_h(t1 + 1, 0, 3);
    BARRIER(); LGKMCNT0(); SCHEDB();
    MFMA_Q(0, 0, nf0);
    BARRIER();
    READ_NF(As1, 1, nf1);
    if (more) stage_h(t1 + 1, 0, 1);
    BARRIER(); LGKMCNT0(); SCHEDB();
    MFMA_Q(0, 1, nf1);
    BARRIER();
    READ_MF(Bs1, 1);
    if (more) stage_h(t1 + 2, 1, 2);
    BARRIER(); LGKMCNT0(); SCHEDB();
    MFMA_Q(1, 1, nf1);
    BARRIER();
    if (more) { stage_h(t1 + 2, 1, 0); VMCNT4(); } else { VMCNT0(); }
    BARRIER();
    MFMA_Q(1, 0, nf0);
    BARRIER();
  }

  // epilogue (swapped layout): lane = S-row (lr within wn/g), 4 consecutive
  // S-cols (quad*4+r within wm/f). s16x4 stores; 2-shfl cross-quad rowsum.
  constexpr float scale = 0.03125f;
  float rsum[4] = {0.f, 0.f, 0.f, 0.f};
  #pragma unroll
  for (int f = 0; f < 8; f++) {
    const int scolb = col0 + wm * 128 + f * 16 + quad * 4;
    #pragma unroll
    for (int g = 0; g < 4; g++) {
      const int srow = row0 + wn * 64 + g * 16 + lr;
      s16x4 v;
      float es = 0.f;
      #pragma unroll
      for (int r = 0; r < 4; r++) {
        float e = __expf(acc[f][g][r] * scale);
        v[r] = f2b(e);
        es += e;
      }
      *reinterpret_cast<s16x4*>(&SP[(size_t)srow * N_TOK + scolb]) = v;
      rsum[g] += es;
    }
  }
  // lanes l, l^16, l^32 share lr (same rows) -> 2-shfl quad reduce.
  float* sred = reinterpret_cast<float*>(&smem[0][0]);   // 2 x 256 floats
  #pragma unroll
  for (int g = 0; g < 4; g++) {
    float s = rsum[g];
    s += __shfl_xor(s, 16, 64);
    s += __shfl_xor(s, 32, 64);
    if (quad == 0) sred[wm * 256 + wn * 64 + g * 16 + lr] = s;
  }
  __syncthreads();
  if (tid < 256)
    rowsum_p[(size_t)bx * N_TOK + row0 + tid] = sred[tid] + sred[256 + tid];
}

// ---------------------------------------------------------------------------
// R24 k_pv: 128x128 tile, BK=64, 512 threads (8 waves 2Mx4N, per-wave 64x32),
// counted-vmcnt double-buffer (R16 schedule), vmcnt(4), LDS 2x32KB = 64KB.
// Grid (8,32) = 256 blocks. SP staged 8x (was 16x with 64-col tiles).
// Epilogue: O = acc / rowsum (sum of 16 partials, float4 loads).
// ---------------------------------------------------------------------------
__global__ __launch_bounds__(512, 2)
void k_pv(const short* __restrict__ SP, const short* __restrict__ Vt,
          float* __restrict__ out, const float* __restrict__ rowsum_p)
{
  constexpr int BM = 128, BN = 128, BK = 64;
  constexpr int NT = N_TOK / BK;                // 64 K-tiles
  __shared__ short smem[2][(BM + BN) * BK];     // 2 x 16384 shorts = 64 KiB

  int bx = blockIdx.x, by = blockIdx.y;
  xcd_remap(8, bx, by);                         // grid (8,32), bijective
  const int row0 = by * BM, col0 = bx * BN;

  const int tid  = threadIdx.x;
  const int wave = tid >> 6, lane = tid & 63;
  const int wm = wave >> 2, wn = wave & 3;      // 2x4 waves, 64x32 out each
  const int quad = lane >> 4, lr = lane & 15;

  auto stage = [&](int t, int sl) {
    #pragma unroll
    for (int c = 0; c < 4; c++) {
      const int id = c * 512 + tid;             // 0..2047
      const int r  = id >> 3;                   // rows 0..255 (A:0-127, B:128-255)
      const int q  = (id & 7) ^ (r & 7);
      const short* src = (r < BM)
          ? SP + (size_t)(row0 + r) * N_TOK + t * BK + q * 8
          : Vt + (size_t)(col0 + r - BM) * N_TOK + t * BK + q * 8;
      gld_lds16(src, &smem[sl][(c * 512 + wave * 64) * 8]);
    }
  };

  f32x4 acc[4][2];
  #pragma unroll
  for (int i = 0; i < 4; i++)
    #pragma unroll
    for (int j = 0; j < 2; j++) acc[i][j] = {0.f, 0.f, 0.f, 0.f};

  stage(0, 0);
  stage(1, 1);
  VMCNT4();
  BARRIER();

  for (int t = 0; t < NT; t++) {
    const int sl = t & 1;
    const short* As = smem[sl];
    const short* Bs = smem[sl] + BM * BK;

    s16x8 af[2][4], bf[2][2];
    #pragma unroll
    for (int h = 0; h < 2; h++) {
      #pragma unroll
      for (int i = 0; i < 4; i++) {
        const int row = wm * 64 + i * 16 + lr;
        const int ch = (h * 4 + quad) ^ (row & 7);
        af[h][i] = *reinterpret_cast<const s16x8*>(&As[(row * 8 + ch) * 8]);
      }
      #pragma unroll
      for (int j = 0; j < 2; j++) {
        const int row = wn * 32 + j * 16 + lr;
        const int ch = (h * 4 + quad) ^ (row & 7);
        bf[h][j] = *reinterpret_cast<const s16x8*>(&Bs[(row * 8 + ch) * 8]);
      }
    }
    LGKMCNT0();
    SCHEDB();
    BARRIER();                                   // slot sl reusable block-wide

    const bool pf = (t + 2) < NT;
    if (pf) stage(t + 2, sl);

    __builtin_amdgcn_s_setprio(1);
    #pragma unroll
    for (int h = 0; h < 2; h++)
      #pragma unroll
      for (int i = 0; i < 4; i++)
        #pragma unroll
        for (int j = 0; j < 2; j++)
          acc[i][j] = __builtin_amdgcn_mfma_f32_16x16x32_bf16(
              af[h][i], bf[h][j], acc[i][j], 0, 0, 0);
    __builtin_amdgcn_s_setprio(0);

    if (pf) { VMCNT4(); } else { VMCNT0(); }
    BARRIER();
  }

  // epilogue: O = acc / rowsum[row]; rowsum = sum of 16 partials (float4).
  #pragma unroll
  for (int i = 0; i < 4; i++) {
    const int r0 = row0 + wm * 64 + i * 16 + quad * 4;
    float4 rsv = {0.f, 0.f, 0.f, 0.f};
    #pragma unroll
    for (int p = 0; p < 16; p++) {
      float4 v = *reinterpret_cast<const float4*>(&rowsum_p[(size_t)p * N_TOK + r0]);
      rsv.x += v.x; rsv.y += v.y; rsv.z += v.z; rsv.w += v.w;
    }
    float linv[4] = {1.0f / rsv.x, 1.0f / rsv.y, 1.0f / rsv.z, 1.0f / rsv.w};
    #pragma unroll
    for (int j = 0; j < 2; j++) {
      const int c = col0 + wn * 32 + j * 16 + lr;
      #pragma unroll
      for (int r = 0; r < 4; r++)
        out[(size_t)(r0 + r) * DDIM + c] = acc[i][j][r] * linv[r];
    }
  }
}

// ---------------------------------------------------------------------------
extern "C" void kernel_launch(void* const* d_in, const int* in_sizes, int n_in,
                              void* d_out, int out_size, void* d_ws, size_t ws_size,
                              hipStream_t stream)
{
  const float* x  = (const float*)d_in[0];
  const float* Wq = (const float*)d_in[1];
  const float* bq = (const float*)d_in[2];
  const float* Wk = (const float*)d_in[3];
  const float* bk = (const float*)d_in[4];
  const float* Wv = (const float*)d_in[5];
  const float* bv = (const float*)d_in[6];
  float* out = (float*)d_out;

  char* ws = (char*)d_ws;
  const size_t MB = 1024 * 1024;
  short* Qb  = (short*)(ws + 0 * MB);
  short* Kb  = (short*)(ws + 8 * MB);
  short* Vt  = (short*)(ws + 24 * MB);
  short* SP  = (short*)(ws + 32 * MB);   // 32 MB (32..64MB)
  short* xb  = (short*)(ws + 32 * MB);   // overlaps SP (dead before k_score)
  short* Wqb = (short*)(ws + 40 * MB);
  short* Wkb = (short*)(ws + 42 * MB);
  short* Wvb = (short*)(ws + 44 * MB);
  float* rowsum_p = (float*)(ws + 64 * MB); // fp32[16][4096], past SP

  dim3 b256(256);

  // fp32 -> bf16 for x and the three W's
  cvt_all<<<dim3(NCVT), b256, 0, stream>>>(
      x, Wq, Wk, Wv, xb, Wqb, Wkb, Wvb);

  // Q/K = x @ W^T + b (bf16); V-slice writes Vt transposed; dbuf-pipelined
  k_qkv<<<dim3(DDIM / 128, N_TOK / 128, 3), b256, 0, stream>>>(
      xb, Wqb, Wkb, Wvb, bq, bk, bv, Qb, Kb, Vt);

  // P = exp(Q @ K^T / 32) (bf16) + rowsum partials; 8-phase swapped-operand
  k_score<<<dim3(16, 16), dim3(512), 0, stream>>>(Qb, Kb, SP, rowsum_p);

  // O = (P @ Vt^T) / rowsum (fp32 out), 128x128 512-thr dbuf, vmcnt(4)
  k_pv<<<dim3(8, 32), dim3(512), 0, stream>>>(
      SP, Vt, out, rowsum_p);
}

// Round 12
// 192.586 us; speedup vs baseline: 1.0436x; 1.0436x over previous
//
#include <hip/hip_runtime.h>

// N=4096, D=1024 self-attention, all GEMMs NT-form bf16 MFMA (16x16x32), fp32 acc.
// R4: BK=64 + XOR swizzle. R5: XCD swizzle. R7: softmax fused into epilogues.
// R12: V-transpose fused into k_qkv (MODE 3).
// R14 (REVERTED): BK=32 ring. R15 (REVERTED): split-K atomics.
// R16 (WIN, 213->207): k_score counted-vmcnt double-buffer (T3+T4+T5).
// R17 (WIN, 207->200): same on k_pv. R18 (WIN, 200->197.7): on k_qkv.
// R19/R20 (NEUTRAL, ->196.8): k_score 8-phase 256x256. Kept.
// R21 (REVERTED, 272): fused-QKV blew registers + BK=32 bank conflicts.
//   RULE: the chunk-XOR swizzle needs BK=64 row stride.
// R22 (WIN, ->194.5): rowsum atomics -> per-bx partials (LDS reduce).
// R23 (NEUTRAL, ->195.3): k_score operand swap. Kept (lighter epilogue).
// R24 (REVERTED, 201): k_pv 128x128/512thr: FETCH unchanged (SP re-reads were
//   L3-absorbed -- staging cuts only pay in HBM bytes) and grid 256 lost the
//   2nd blk/CU. RULE: keep >=2 blk/CU for the counted-vmcnt template.
// R25: k_pv reverted to R23 config (128x64, 256thr, grid 512) with
//   launch_bounds(256,3) -> 3 blk/CU (LDS 3x48KB=144<=160KB): TLP attacks the
//   remaining barrier-drain exposure (occupancy 17-19% -> ~25%).
//
// ws layout:
//   Qb bf16[4096,1024] @ 0      Kb @ 8MB     Vt bf16[1024,4096] @ 24MB
//   SP bf16[4096,4096] @ 32MB   (exp'd scores; spans 32..64MB)
//   xb @ 32MB (overlaps SP; dead before k_score), Wqb @ 40MB, Wkb @ 42MB, Wvb @ 44MB
//   rowsum_p fp32[16][4096] @ 64MB (past SP; ws >= 112MB proven in R3)

#define N_TOK 4096
#define DDIM  1024

typedef short s16x4 __attribute__((ext_vector_type(4)));
typedef short s16x8 __attribute__((ext_vector_type(8)));
typedef float f32x4 __attribute__((ext_vector_type(4)));

#define VMCNT0() asm volatile("s_waitcnt vmcnt(0)" ::: "memory")
#define VMCNT4() asm volatile("s_waitcnt vmcnt(4)" ::: "memory")
#define VMCNT6() asm volatile("s_waitcnt vmcnt(6)" ::: "memory")
#define VMCNT8() asm volatile("s_waitcnt vmcnt(8)" ::: "memory")
#define LGKMCNT0() asm volatile("s_waitcnt lgkmcnt(0)" ::: "memory")
#define SCHEDB() __builtin_amdgcn_sched_barrier(0)
#define BARRIER() do { asm volatile("" ::: "memory"); \
                       __builtin_amdgcn_s_barrier();  \
                       asm volatile("" ::: "memory"); } while (0)

__device__ inline short f2b(float f) {
  unsigned int u = __float_as_uint(f);
  unsigned int r = (u + 0x7FFFu + ((u >> 16) & 1u)) >> 16;
  return (short)(unsigned short)r;
}

__device__ __forceinline__ void gld_lds16(const short* g, short* l) {
  __builtin_amdgcn_global_load_lds(
      (const __attribute__((address_space(1))) unsigned int*)g,
      (__attribute__((address_space(3))) unsigned int*)l, 16, 0, 0);
}

// XCD-locality remap, GY=32 grids: XCD (L%8) owns a 4-row-tile band.
__device__ __forceinline__ void xcd_remap(int gx, int& bx, int& by) {
  const int L = by * gx + bx;
  const int g = L & 7, h = L >> 3;
  by = g * 4 + (h & 3);
  bx = h >> 2;
}
// 256-tile variant: XCD owns a 2-row-tile band.
__device__ __forceinline__ void xcd_remap16(int gx, int& bx, int& by) {
  const int L = by * gx + bx;
  const int g = L & 7, h = L >> 3;
  by = g * 2 + (h & 1);
  bx = h >> 1;
}

// ---------------------------------------------------------------------------
// R18 pipelined 128x128 BK=64 NT GEMM (R16 schedule). MODE epilogues:
//   0: bf16 store of scale*acc + bias                  (aux = bias)
//   3: bf16 TRANSPOSED store of acc + bias             (aux = bias)
// smem: 2 slots x 16384 shorts (64 KiB). ldA == ldB == ld.
// ---------------------------------------------------------------------------
template<int MODE>
__device__ __forceinline__ void gemm_pipe128(
    const short* __restrict__ A, const short* __restrict__ B,
    void* __restrict__ C, const float* __restrict__ aux,
    short (*smem)[(128 + 128) * 64],
    int K, int ld, int ldc, float scale, int row0, int col0)
{
  constexpr int BM = 128, BN = 128, BK = 64;
  const int NT = K / BK;

  const int tid  = threadIdx.x;
  const int wave = tid >> 6, lane = tid & 63;
  const int wm = wave >> 1, wn = wave & 1;      // 2x2 waves, 64x64 out each
  const int quad = lane >> 4, lr = lane & 15;

  auto stage = [&](int t, int sl) {
    #pragma unroll
    for (int c = 0; c < 8; c++) {
      const int id = c * 256 + tid;             // 0..2047
      const int r  = id >> 3;                   // rows 0..255 (A:0-127, B:128-255)
      const int q  = (id & 7) ^ (r & 7);
      const short* src = (r < BM)
          ? A + (size_t)(row0 + r) * ld + t * BK + q * 8
          : B + (size_t)(col0 + r - BM) * ld + t * BK + q * 8;
      gld_lds16(src, &smem[sl][(c * 256 + wave * 64) * 8]);
    }
  };

  f32x4 acc[4][4];
  #pragma unroll
  for (int i = 0; i < 4; i++)
    #pragma unroll
    for (int j = 0; j < 4; j++) acc[i][j] = {0.f, 0.f, 0.f, 0.f};

  stage(0, 0);
  stage(1, 1);
  VMCNT8();
  BARRIER();

  for (int t = 0; t < NT; t++) {
    const int sl = t & 1;
    const short* As = smem[sl];
    const short* Bs = smem[sl] + BM * BK;

    s16x8 af[2][4], bf[2][4];
    #pragma unroll
    for (int h = 0; h < 2; h++) {
      #pragma unroll
      for (int i = 0; i < 4; i++) {
        const int row = wm * 64 + i * 16 + lr;
        const int ch = (h * 4 + quad) ^ (row & 7);
        af[h][i] = *reinterpret_cast<const s16x8*>(&As[(row * 8 + ch) * 8]);
      }
      #pragma unroll
      for (int j = 0; j < 4; j++) {
        const int row = wn * 64 + j * 16 + lr;
        const int ch = (h * 4 + quad) ^ (row & 7);
        bf[h][j] = *reinterpret_cast<const s16x8*>(&Bs[(row * 8 + ch) * 8]);
      }
    }
    LGKMCNT0();
    SCHEDB();
    BARRIER();                                   // slot sl reusable block-wide

    const bool pf = (t + 2) < NT;
    if (pf) stage(t + 2, sl);

    __builtin_amdgcn_s_setprio(1);
    #pragma unroll
    for (int h = 0; h < 2; h++)
      #pragma unroll
      for (int i = 0; i < 4; i++)
        #pragma unroll
        for (int j = 0; j < 4; j++)
          acc[i][j] = __builtin_amdgcn_mfma_f32_16x16x32_bf16(
              af[h][i], bf[h][j], acc[i][j], 0, 0, 0);
    __builtin_amdgcn_s_setprio(0);

    if (pf) { VMCNT8(); } else { VMCNT0(); }
    BARRIER();
  }
  // loop exit: all LDS reads drained (tail vmcnt(0)+barrier) -> smem reusable.

  if constexpr (MODE == 0) {
    float bb[4];
    #pragma unroll
    for (int j = 0; j < 4; j++) bb[j] = aux[col0 + wn * 64 + j * 16 + lr];
    #pragma unroll
    for (int i = 0; i < 4; i++) {
      const int r0 = row0 + wm * 64 + i * 16 + quad * 4;
      #pragma unroll
      for (int j = 0; j < 4; j++) {
        const int c = col0 + wn * 64 + j * 16 + lr;
        #pragma unroll
        for (int r = 0; r < 4; r++)
          ((short*)C)[(size_t)(r0 + r) * ldc + c] = f2b(acc[i][j][r] * scale + bb[j]);
      }
    }
  } else {
    // MODE 3: transposed bf16 store with bias. trans[col][row], stride 136.
    float bb[4];
    #pragma unroll
    for (int j = 0; j < 4; j++) bb[j] = aux[col0 + wn * 64 + j * 16 + lr];
    short* trans = &smem[0][0];                  // 128 x 136 shorts = 34816 B
    #pragma unroll
    for (int i = 0; i < 4; i++) {
      const int rl = wm * 64 + i * 16 + quad * 4;
      #pragma unroll
      for (int j = 0; j < 4; j++) {
        const int cl = wn * 64 + j * 16 + lr;
        s16x4 v;
        #pragma unroll
        for (int r = 0; r < 4; r++) v[r] = f2b(acc[i][j][r] * scale + bb[j]);
        *reinterpret_cast<s16x4*>(&trans[cl * 136 + rl]) = v;
      }
    }
    BARRIER();
    #pragma unroll
    for (int s = 0; s < 8; s++) {
      const int u = s * 256 + tid;
      const int cc = u >> 4;                     // column 0..127
      const int seg = u & 15;                    // 16 segs x 8 shorts = 128 rows
      s16x8 v = *reinterpret_cast<const s16x8*>(&trans[cc * 136 + seg * 8]);
      *reinterpret_cast<s16x8*>(
          &((short*)C)[(size_t)(col0 + cc) * ldc + row0 + seg * 8]) = v;
    }
  }
}

// ---------------------------------------------------------------------------
// fp32 -> bf16 conversion for x, Wq, Wk, Wv (one launch).
// ---------------------------------------------------------------------------
#define XU  (N_TOK * DDIM / 8)      // 524288
#define WU  (DDIM * DDIM / 8)       // 131072
#define NCVT ((XU + 3 * WU) / 256)  // 3584 convert blocks
__global__ __launch_bounds__(256)
void cvt_all(const float* __restrict__ x,  const float* __restrict__ wq,
             const float* __restrict__ wk, const float* __restrict__ wv,
             short* __restrict__ xb, short* __restrict__ wqb,
             short* __restrict__ wkb, short* __restrict__ wvb)
{
  int gid = blockIdx.x * 256 + threadIdx.x;
  const float* src; short* dst; int off;
  if (gid < XU)               { src = x;  dst = xb;  off = gid; }
  else if (gid < XU + WU)     { src = wq; dst = wqb; off = gid - XU; }
  else if (gid < XU + 2 * WU) { src = wk; dst = wkb; off = gid - XU - WU; }
  else                        { src = wv; dst = wvb; off = gid - XU - 2 * WU; }
  const float4* g = reinterpret_cast<const float4*>(src) + (size_t)off * 2;
  float4 a = g[0], b = g[1];
  s16x8 o;
  o[0] = f2b(a.x); o[1] = f2b(a.y); o[2] = f2b(a.z); o[3] = f2b(a.w);
  o[4] = f2b(b.x); o[5] = f2b(b.y); o[6] = f2b(b.z); o[7] = f2b(b.w);
  reinterpret_cast<s16x8*>(dst)[off] = o;
}

// ---------------------------------------------------------------------------
// R18 k_qkv: pipelined 128x128 BK=64; grid (8,32,3); LDS 64KB -> 2 blk/CU.
// ---------------------------------------------------------------------------
__global__ __launch_bounds__(256, 2)
void k_qkv(const short* __restrict__ xb,
           const short* __restrict__ Wqb, const short* __restrict__ Wkb,
           const short* __restrict__ Wvb,
           const float* __restrict__ bq, const float* __restrict__ bk,
           const float* __restrict__ bv,
           short* __restrict__ Qb, short* __restrict__ Kb, short* __restrict__ Vt)
{
  __shared__ short smem[2][(128 + 128) * 64];   // 64 KiB
  int bx = blockIdx.x, by = blockIdx.y;
  xcd_remap(DDIM / 128, bx, by);
  if (blockIdx.z == 0) {
    gemm_pipe128<0>(xb, Wqb, Qb, bq, smem, DDIM, DDIM, DDIM,
                    1.0f, by * 128, bx * 128);
  } else if (blockIdx.z == 1) {
    gemm_pipe128<0>(xb, Wkb, Kb, bk, smem, DDIM, DDIM, DDIM,
                    1.0f, by * 128, bx * 128);
  } else {
    gemm_pipe128<3>(xb, Wvb, Vt, bv, smem, DDIM, DDIM, N_TOK,
                    1.0f, by * 128, bx * 128);
  }
}

// ---------------------------------------------------------------------------
// R23 k_score: 8-phase 256x256 BK=64, 512 threads, 128KB LDS, OPERAND SWAP:
// mfma(A=K_frag, B=Q_frag) -> D[m=S-col][n=S-row]. Lane holds 4 consecutive
// S-cols (quad*4+r) of one S-row (lr). Epilogue: s16x4 SP stores, 2-shfl
// cross-quad rowsum, 2-partial LDS reduce, non-atomic rowsum_p[bx] store.
// ---------------------------------------------------------------------------
#define READ_MF(Bs, MH) do {                                                  \
    _Pragma("unroll")                                                         \
    for (int kh = 0; kh < 2; kh++)                                            \
      _Pragma("unroll")                                                       \
      for (int f = 0; f < 4; f++) {                                           \
        const int row_ = wm * 128 + (MH) * 64 + f * 16 + lr;                  \
        const int ch_ = (kh * 4 + quad) ^ (row_ & 7);                         \
        mf[kh][f] = *reinterpret_cast<const s16x8*>(&(Bs)[(row_ * 8 + ch_) * 8]); \
      }                                                                       \
  } while (0)

#define READ_NF(As, NH, NF) do {                                              \
    _Pragma("unroll")                                                         \
    for (int kh = 0; kh < 2; kh++)                                            \
      _Pragma("unroll")                                                       \
      for (int g = 0; g < 2; g++) {                                           \
        const int row_ = wn * 64 + (NH) * 32 + g * 16 + lr;                   \
        const int ch_ = (kh * 4 + quad) ^ (row_ & 7);                         \
        NF[kh][g] = *reinterpret_cast<const s16x8*>(&(As)[(row_ * 8 + ch_) * 8]); \
      }                                                                       \
  } while (0)

#define MFMA_Q(MH, NH, NF) do {                                               \
    __builtin_amdgcn_s_setprio(1);                                            \
    _Pragma("unroll")                                                         \
    for (int kh = 0; kh < 2; kh++)                                            \
      _Pragma("unroll")                                                       \
      for (int f = 0; f < 4; f++)                                             \
        _Pragma("unroll")                                                     \
        for (int g = 0; g < 2; g++)                                           \
          acc[(MH) * 4 + f][(NH) * 2 + g] =                                   \
              __builtin_amdgcn_mfma_f32_16x16x32_bf16(                        \
                  mf[kh][f], NF[kh][g], acc[(MH) * 4 + f][(NH) * 2 + g],      \
                  0, 0, 0);                                                   \
    __builtin_amdgcn_s_setprio(0);                                            \
  } while (0)

__global__ __launch_bounds__(512, 2)
void k_score(const short* __restrict__ Qb, const short* __restrict__ Kb,
             short* __restrict__ SP, float* __restrict__ rowsum_p)
{
  constexpr int NITER = 8;                      // 16 K-tiles, 2 per iter
  __shared__ short smem[2][32768];              // [buf][Q 256x64 | K 256x64] 128KB

  int bx = blockIdx.x, by = blockIdx.y;
  xcd_remap16(16, bx, by);
  const int row0 = by * 256, col0 = bx * 256;   // row0: Q rows, col0: K rows

  const int tid  = threadIdx.x;
  const int wave = tid >> 6, lane = tid & 63;
  const int wm = wave >> 2, wn = wave & 3;      // wm: 128 S-cols, wn: 64 S-rows
  const int quad = lane >> 4, lr = lane & 15;

  auto stage_h = [&](int t, int b, int h) {
    const short* gbase = (h < 2)
        ? Qb + (size_t)(row0 + (h & 1) * 128) * DDIM
        : Kb + (size_t)(col0 + (h & 1) * 128) * DDIM;
    short* dst = &smem[b][(h >> 1) * 16384 + (h & 1) * 8192];
    #pragma unroll
    for (int c = 0; c < 2; c++) {
      const int id = c * 512 + tid;             // 0..1023
      const int r  = id >> 3;                   // 0..127
      const int q  = (id & 7) ^ (r & 7);
      gld_lds16(gbase + (size_t)r * DDIM + t * 64 + q * 8,
                dst + (c * 512 + wave * 64) * 8);
    }
  };

  s16x8 mf[2][4], nf0[2][2], nf1[2][2];
  f32x4 acc[8][4];
  #pragma unroll
  for (int i = 0; i < 8; i++)
    #pragma unroll
    for (int j = 0; j < 4; j++) acc[i][j] = {0.f, 0.f, 0.f, 0.f};

  const short* As0 = smem[0];                   // Q half
  const short* Bs0 = smem[0] + 16384;           // K half
  const short* As1 = smem[1];
  const short* Bs1 = smem[1] + 16384;

  stage_h(0, 0, 2); stage_h(0, 0, 3); stage_h(0, 0, 0); stage_h(0, 0, 1);
  stage_h(1, 1, 2); stage_h(1, 1, 0);
  VMCNT4();
  BARRIER();

  for (int i = 0; i < NITER; i++) {
    const int t1 = 2 * i + 1;
    const bool more = (i + 1) < NITER;

    READ_MF(Bs0, 0); READ_NF(As0, 0, nf0);
    stage_h(t1, 1, 3);
    BARRIER(); LGKMCNT0(); SCHEDB();
    MFMA_Q(0, 0, nf0);
    BARRIER();
    READ_NF(As0, 1, nf1);
    stage_h(t1, 1, 1);
    BARRIER(); LGKMCNT0(); SCHEDB();
    MFMA_Q(0, 1, nf1);
    BARRIER();
    READ_MF(Bs0, 1);
    if (more) stage_h(t1 + 1, 0, 2);
    BARRIER(); LGKMCNT0(); SCHEDB();
    MFMA_Q(1, 1, nf1);
    BARRIER();
    if (more) { stage_h(t1 + 1, 0, 0); VMCNT4(); } else { VMCNT0(); }
    BARRIER();
    MFMA_Q(1, 0, nf0);
    BARRIER();
    READ_MF(Bs1, 0); READ_NF(As1, 0, nf0);
    if (more) stage_h(t1 + 1, 0, 3);
    BARRIER(); LGKMCNT0(); SCHEDB();
    MFMA_Q(0, 0, nf0);
    BARRIER();
    READ_NF(As1, 1, nf1);
    if (more) stage_h(t1 + 1, 0, 1);
    BARRIER(); LGKMCNT0(); SCHEDB();
    MFMA_Q(0, 1, nf1);
    BARRIER();
    READ_MF(Bs1, 1);
    if (more) stage_h(t1 + 2, 1, 2);
    BARRIER(); LGKMCNT0(); SCHEDB();
    MFMA_Q(1, 1, nf1);
    BARRIER();
    if (more) { stage_h(t1 + 2, 1, 0); VMCNT4(); } else { VMCNT0(); }
    BARRIER();
    MFMA_Q(1, 0, nf0);
    BARRIER();
  }

  // epilogue (swapped layout): lane = S-row (lr within wn/g), 4 consecutive
  // S-cols (quad*4+r within wm/f). s16x4 stores; 2-shfl cross-quad rowsum.
  constexpr float scale = 0.03125f;
  float rsum[4] = {0.f, 0.f, 0.f, 0.f};
  #pragma unroll
  for (int f = 0; f < 8; f++) {
    const int scolb = col0 + wm * 128 + f * 16 + quad * 4;
    #pragma unroll
    for (int g = 0; g < 4; g++) {
      const int srow = row0 + wn * 64 + g * 16 + lr;
      s16x4 v;
      float es = 0.f;
      #pragma unroll
      for (int r = 0; r < 4; r++) {
        float e = __expf(acc[f][g][r] * scale);
        v[r] = f2b(e);
        es += e;
      }
      *reinterpret_cast<s16x4*>(&SP[(size_t)srow * N_TOK + scolb]) = v;
      rsum[g] += es;
    }
  }
  // lanes l, l^16, l^32 share lr (same rows) -> 2-shfl quad reduce.
  float* sred = reinterpret_cast<float*>(&smem[0][0]);   // 2 x 256 floats
  #pragma unroll
  for (int g = 0; g < 4; g++) {
    float s = rsum[g];
    s += __shfl_xor(s, 16, 64);
    s += __shfl_xor(s, 32, 64);
    if (quad == 0) sred[wm * 256 + wn * 64 + g * 16 + lr] = s;
  }
  __syncthreads();
  if (tid < 256)
    rowsum_p[(size_t)bx * N_TOK + row0 + tid] = sred[tid] + sred[256 + tid];
}

// ---------------------------------------------------------------------------
// R25 k_pv: 128x64 tile, BK=64, 256 threads, counted-vmcnt double-buffer.
// Grid (16,32)=512; LDS 2x24KB=48KB; launch_bounds(256,3) -> 3 blk/CU
// (3x48KB=144<=160KB LDS, VGPR 72 fits 3 waves/SIMD). vmcnt(6).
// Epilogue: O = acc / rowsum (sum of 16 partials, float4 loads).
// ---------------------------------------------------------------------------
__global__ __launch_bounds__(256, 3)
void k_pv(const short* __restrict__ SP, const short* __restrict__ Vt,
          float* __restrict__ out, const float* __restrict__ rowsum_p)
{
  constexpr int BM = 128, BN = 64, BK = 64;
  constexpr int NT = N_TOK / BK;                // 64 K-tiles
  __shared__ short smem[2][(BM + BN) * BK];     // 2 x 12288 shorts = 48 KiB

  int bx = blockIdx.x, by = blockIdx.y;
  xcd_remap(DDIM / 64, bx, by);
  const int row0 = by * BM, col0 = bx * BN;

  const int tid  = threadIdx.x;
  const int wave = tid >> 6, lane = tid & 63;
  const int wm = wave >> 1, wn = wave & 1;      // 2x2 waves, 64x32 out each
  const int quad = lane >> 4, lr = lane & 15;

  auto stage = [&](int t, int sl) {
    #pragma unroll
    for (int c = 0; c < 6; c++) {
      const int id = c * 256 + tid;             // 0..1535
      const int r  = id >> 3;                   // rows 0..191 (A:0-127, B:128-191)
      const int q  = (id & 7) ^ (r & 7);
      const short* src = (r < BM)
          ? SP + (size_t)(row0 + r) * N_TOK + t * BK + q * 8
          : Vt + (size_t)(col0 + r - BM) * N_TOK + t * BK + q * 8;
      gld_lds16(src, &smem[sl][(c * 256 + wave * 64) * 8]);
    }
  };

  f32x4 acc[4][2];
  #pragma unroll
  for (int i = 0; i < 4; i++)
    #pragma unroll
    for (int j = 0; j < 2; j++) acc[i][j] = {0.f, 0.f, 0.f, 0.f};

  stage(0, 0);
  stage(1, 1);
  VMCNT6();
  BARRIER();

  for (int t = 0; t < NT; t++) {
    const int sl = t & 1;
    const short* As = smem[sl];
    const short* Bs = smem[sl] + BM * BK;

    s16x8 af[2][4], bf[2][2];
    #pragma unroll
    for (int h = 0; h < 2; h++) {
      #pragma unroll
      for (int i = 0; i < 4; i++) {
        const int row = wm * 64 + i * 16 + lr;
        const int ch = (h * 4 + quad) ^ (row & 7);
        af[h][i] = *reinterpret_cast<const s16x8*>(&As[(row * 8 + ch) * 8]);
      }
      #pragma unroll
      for (int j = 0; j < 2; j++) {
        const int row = wn * 32 + j * 16 + lr;
        const int ch = (h * 4 + quad) ^ (row & 7);
        bf[h][j] = *reinterpret_cast<const s16x8*>(&Bs[(row * 8 + ch) * 8]);
      }
    }
    LGKMCNT0();
    SCHEDB();
    BARRIER();                                   // slot sl reusable block-wide

    const bool pf = (t + 2) < NT;
    if (pf) stage(t + 2, sl);

    __builtin_amdgcn_s_setprio(1);
    #pragma unroll
    for (int h = 0; h < 2; h++)
      #pragma unroll
      for (int i = 0; i < 4; i++)
        #pragma unroll
        for (int j = 0; j < 2; j++)
          acc[i][j] = __builtin_amdgcn_mfma_f32_16x16x32_bf16(
              af[h][i], bf[h][j], acc[i][j], 0, 0, 0);
    __builtin_amdgcn_s_setprio(0);

    if (pf) { VMCNT6(); } else { VMCNT0(); }
    BARRIER();
  }

  // epilogue: O = acc / rowsum[row]; rowsum = sum of 16 partials (float4).
  #pragma unroll
  for (int i = 0; i < 4; i++) {
    const int r0 = row0 + wm * 64 + i * 16 + quad * 4;
    float4 rsv = {0.f, 0.f, 0.f, 0.f};
    #pragma unroll
    for (int p = 0; p < 16; p++) {
      float4 v = *reinterpret_cast<const float4*>(&rowsum_p[(size_t)p * N_TOK + r0]);
      rsv.x += v.x; rsv.y += v.y; rsv.z += v.z; rsv.w += v.w;
    }
    float linv[4] = {1.0f / rsv.x, 1.0f / rsv.y, 1.0f / rsv.z, 1.0f / rsv.w};
    #pragma unroll
    for (int j = 0; j < 2; j++) {
      const int c = col0 + wn * 32 + j * 16 + lr;
      #pragma unroll
      for (int r = 0; r < 4; r++)
        out[(size_t)(r0 + r) * DDIM + c] = acc[i][j][r] * linv[r];
    }
  }
}

// ---------------------------------------------------------------------------
extern "C" void kernel_launch(void* const* d_in, const int* in_sizes, int n_in,
                              void* d_out, int out_size, void* d_ws, size_t ws_size,
                              hipStream_t stream)
{
  const float* x  = (const float*)d_in[0];
  const float* Wq = (const float*)d_in[1];
  const float* bq = (const float*)d_in[2];
  const float* Wk = (const float*)d_in[3];
  const float* bk = (const float*)d_in[4];
  const float* Wv = (const float*)d_in[5];
  const float* bv = (const float*)d_in[6];
  float* out = (float*)d_out;

  char* ws = (char*)d_ws;
  const size_t MB = 1024 * 1024;
  short* Qb  = (short*)(ws + 0 * MB);
  short* Kb  = (short*)(ws + 8 * MB);
  short* Vt  = (short*)(ws + 24 * MB);
  short* SP  = (short*)(ws + 32 * MB);   // 32 MB (32..64MB)
  short* xb  = (short*)(ws + 32 * MB);   // overlaps SP (dead before k_score)
  short* Wqb = (short*)(ws + 40 * MB);
  short* Wkb = (short*)(ws + 42 * MB);
  short* Wvb = (short*)(ws + 44 * MB);
  float* rowsum_p = (float*)(ws + 64 * MB); // fp32[16][4096], past SP

  dim3 b256(256);

  // fp32 -> bf16 for x and the three W's
  cvt_all<<<dim3(NCVT), b256, 0, stream>>>(
      x, Wq, Wk, Wv, xb, Wqb, Wkb, Wvb);

  // Q/K = x @ W^T + b (bf16); V-slice writes Vt transposed; dbuf-pipelined
  k_qkv<<<dim3(DDIM / 128, N_TOK / 128, 3), b256, 0, stream>>>(
      xb, Wqb, Wkb, Wvb, bq, bk, bv, Qb, Kb, Vt);

  // P = exp(Q @ K^T / 32) (bf16) + rowsum partials; 8-phase swapped-operand
  k_score<<<dim3(16, 16), dim3(512), 0, stream>>>(Qb, Kb, SP, rowsum_p);

  // O = (P @ Vt^T) / rowsum (fp32 out), 128x64 dbuf, 3 blk/CU
  k_pv<<<dim3(DDIM / 64, N_TOK / 128), b256, 0, stream>>>(
      SP, Vt, out, rowsum_p);
}